// Round 8
// baseline (3437.082 us; speedup 1.0000x reference)
//
#include <hip/hip_runtime.h>

// AttentionRNN: B=1024, T=256, U=256.
//  Xh = fp16(X); P[t] = x_t @ [Wemb|Wre|Wnew] (fp16 MFMA GEMM, CT=16 chunks).
//  Recurrent: 128 blocks x 8 rows x 16 waves (4 waves/SIMD). Wave pair (2r,2r+1)
//  owns batch row r: phase 1 = 64 qg cols/wave via MFMA (2-deep cross-step weight
//  pipeline); phase 2a = scores partials (2 cols/lane, LDS combine); phase 2b =
//  softmax + GRU (2 cols/lane). Rolling registers: each P element read once.
//  lgkm-only barriers keep global loads in flight. qg in 10-word groups (no
//  bank conflicts, 8B aligned). P slabs for t=-2,-1 zeroed (no branches).

typedef _Float16 f16;
typedef _Float16 f16x8 __attribute__((ext_vector_type(8)));
typedef _Float16 f16x2 __attribute__((ext_vector_type(2)));
typedef float f32x4 __attribute__((ext_vector_type(4)));
typedef float f32x2 __attribute__((ext_vector_type(2)));

static __device__ __forceinline__ f32x4 mfma16(f16x8 a, f16x8 b, f32x4 c){
  return __builtin_amdgcn_mfma_f32_16x16x32_f16(a, b, c, 0, 0, 0);
}
static __device__ __forceinline__ float sigmoid_f(float x){
  return 1.0f / (1.0f + __expf(-x));
}
static __device__ __forceinline__ float tanh_f(float x){
  float e = __expf(2.0f * x);
  return 1.0f - 2.0f / (e + 1.0f);   // stable
}
static __device__ __forceinline__ void lgkm_barrier(){
  asm volatile("s_waitcnt lgkmcnt(0)" ::: "memory");
  __builtin_amdgcn_s_barrier();
}

// ---------------- cast X fp32 -> fp16 (same layout) ----------------
__global__ void cast_x_kernel(const float* __restrict__ X, f16* __restrict__ Xh){
  size_t e = ((size_t)blockIdx.x * 256 + threadIdx.x) * 8;
  f32x4 v0 = *(const f32x4*)(X + e);
  f32x4 v1 = *(const f32x4*)(X + e + 4);
  f16x8 h;
  #pragma unroll
  for (int j = 0; j < 8; ++j) h[j] = (f16)((j < 4) ? v0[j] : v1[j-4]);
  *(f16x8*)(Xh + e) = h;
}

// ------------- cast weights to fp16 -------------
// WcatT rows: [0,256) Wemb^T, [256,1024) Wre^T, [1024,1792) Wnew^T  (N x K row-major)
// WsrF fragment-packed [ct64][kt8][lane64][e8]: col=ct*16+(lane&15), k=kt*32+((lane>>4)&3)*8+e
__global__ void cast_w_kernel(const float* __restrict__ EK, const float* __restrict__ RE,
    const float* __restrict__ NW, const float* __restrict__ SK, const float* __restrict__ RS,
    f16* __restrict__ WcatT, f16* __restrict__ WsrF){
  int tid = blockIdx.x * 256 + threadIdx.x;
  if (tid < 458752){
    int n = tid >> 8, k = tid & 255;
    float v;
    if (n < 256)       v = EK[k*256 + n];
    else if (n < 1024) v = RE[k*768 + (n-256)];
    else               v = NW[k*768 + (n-1024)];
    WcatT[n*256 + k] = (f16)v;
  } else {
    int idx = tid - 458752;            // 0..262143
    int e    = idx & 7;
    int lane = (idx >> 3) & 63;
    int kt   = (idx >> 9) & 7;
    int ct   = idx >> 12;              // 0..63
    int col  = ct*16 + (lane & 15);
    int k    = kt*32 + ((lane >> 4) & 3)*8 + e;
    float v = (col < 256) ? SK[k*256 + col] : RS[k*768 + (col-256)];
    WsrF[idx] = (f16)v;
  }
}

// ---- GEMM: C[r=tsl*1024+b][0:1792) = Xh[b][t_start+tsl][:] @ WcatT^T ----
__global__ __launch_bounds__(256, 2) void gemm_f16_kernel(
    const f16* __restrict__ Xh, const f16* __restrict__ Bm,
    f16* __restrict__ C, int Mtiles, int t_start)
{
  __shared__ f16 As[128*64];
  __shared__ f16 Bs[128*64];
  const int NT = 14;
  const int nwg = Mtiles * NT;
  int bid = blockIdx.x, wg = bid;
  if ((nwg & 7) == 0){ int cpx = nwg >> 3; wg = (bid & 7) * cpx + (bid >> 3); }
  const int mt = wg / NT, nt = wg % NT;
  const int tsl = mt >> 3;
  const int b0  = (mt & 7) * 128;
  const int t   = t_start + tsl;
  const int n0  = nt * 128;
  const int tid = threadIdx.x;
  const int l = tid & 63, wid = tid >> 6;
  const int wr = wid >> 1, wc = wid & 1;
  const int srow = tid >> 3;
  const int scol = (tid & 7) * 8;

  const size_t ASTR = 32ull * 65536ull;
  const f16* Ab = Xh + ((size_t)(b0 + srow) * 256 + t) * 256 + scol;
  const f16* Bb = Bm + ((size_t)(n0 + srow)) * 256 + scol;

  f16x8 ra[4], rb[4];
  #pragma unroll
  for (int j = 0; j < 4; ++j){
    ra[j] = *(const f16x8*)(Ab + (size_t)j * ASTR);
    rb[j] = *(const f16x8*)(Bb + (size_t)j * 32 * 256);
  }

  f32x4 acc[4][4];
  #pragma unroll
  for (int mi = 0; mi < 4; ++mi)
    #pragma unroll
    for (int ni = 0; ni < 4; ++ni)
      acc[mi][ni] = (f32x4){0.f,0.f,0.f,0.f};

  for (int kt = 0; kt < 4; ++kt){
    #pragma unroll
    for (int j = 0; j < 4; ++j){
      int row = srow + j*32;
      int e = (row*64 + scol) ^ ((row & 7) << 3);
      *(f16x8*)&As[e] = ra[j];
      *(f16x8*)&Bs[e] = rb[j];
    }
    __syncthreads();
    if (kt < 3){
      #pragma unroll
      for (int j = 0; j < 4; ++j){
        ra[j] = *(const f16x8*)(Ab + (kt+1)*64 + (size_t)j * ASTR);
        rb[j] = *(const f16x8*)(Bb + (kt+1)*64 + (size_t)j * 32 * 256);
      }
    }
    #pragma unroll
    for (int kk = 0; kk < 2; ++kk){
      f16x8 af[4], bfr[4];
      #pragma unroll
      for (int mi = 0; mi < 4; ++mi){
        int row = wr*64 + mi*16 + (l & 15);
        int e = (row*64 + kk*32 + (l >> 4)*8) ^ ((row & 7) << 3);
        af[mi] = *(const f16x8*)&As[e];
      }
      #pragma unroll
      for (int ni = 0; ni < 4; ++ni){
        int row = wc*64 + ni*16 + (l & 15);
        int e = (row*64 + kk*32 + (l >> 4)*8) ^ ((row & 7) << 3);
        bfr[ni] = *(const f16x8*)&Bs[e];
      }
      #pragma unroll
      for (int mi = 0; mi < 4; ++mi)
        #pragma unroll
        for (int ni = 0; ni < 4; ++ni)
          acc[mi][ni] = mfma16(af[mi], bfr[ni], acc[mi][ni]);
    }
    __syncthreads();
  }
  const size_t m0 = (size_t)mt * 128;
  #pragma unroll
  for (int mi = 0; mi < 4; ++mi){
    #pragma unroll
    for (int ni = 0; ni < 4; ++ni){
      int col = n0 + wc*64 + ni*16 + (l & 15);
      size_t row = m0 + wr*64 + mi*16 + ((l >> 4) * 4);
      #pragma unroll
      for (int j = 0; j < 4; ++j)
        C[(row + j) * 1792 + col] = (f16)acc[mi][ni][j];
    }
  }
}

// one kt-stage: 4 MFMAs, then refill av (LDS, 2-deep) and this W slot with kt+2
// ((KT+2)&7: stages 6,7 load next step's kt0,kt1 -- weights are time-invariant).
template<int KT>
static __device__ __forceinline__ void stage2(f32x4 (&acc)[4], f16x8 (&WS)[4], f16x8& av,
    const f16* stA_l, const f16* wb_l){
  #pragma unroll
  for (int c = 0; c < 4; ++c) acc[c] = mfma16(av, WS[c], acc[c]);
  if (KT < 6) av = *(const f16x8*)(stA_l + (KT+2)*520);
  #pragma unroll
  for (int c = 0; c < 4; ++c)
    WS[c] = *(const f16x8*)(wb_l + (c*8 + ((KT+2)&7))*512);
}

// ---------- recurrent: 128 blocks x 8 rows, 1024 threads (16 waves) ----------
__global__ __launch_bounds__(1024, 4) void recurrent_kernel(
    const f16* __restrict__ P, const f16* __restrict__ WsrF,
    const float* __restrict__ bias, const float* __restrict__ Lk,
    float* __restrict__ state, float* __restrict__ out,
    int t0, int nsteps)
{
  __shared__ float qg[8*1280];      // 8 rows x 1024 cols, 10-word groups
  __shared__ f16  stA[8*520];       // state f16, fragment-major [kt][lane][8] + pad
  __shared__ float sb10[320], sl10[320];
  __shared__ float sp[8][2][4];     // per-row per-half score partials

  const int tid = threadIdx.x;
  const int l = tid & 63, w = tid >> 6;          // 16 waves
  const int r0 = blockIdx.x * 8;
  const int agrp = l >> 4;
  const int r = w >> 1, h = w & 1;               // wave pair (r), half (h)
  const int gb = r0 + r;
  const int c2 = h*128 + l*2;                    // 2 cols/lane in [0,256)
  const size_t SL = 1024ull*1792ull;

  const int qw2 = (h*16 + (l >> 2))*10 + 2*(l & 3);          // word of col c2
  const int qgw = (w*8 + ((l & 15) >> 3))*10 + (l & 7);      // phase-1 write base

  if (tid < 256){ int wd = (tid >> 3)*10 + (tid & 7); sb10[wd] = bias[tid]; sl10[wd] = Lk[tid]; }
  for (int j = tid; j < 8*520; j += 1024) stA[j] = (f16)0.f;
  __syncthreads();

  f32x2 sn = *(const f32x2*)(state + (size_t)gb*256 + c2);
  // stA slot for (row r, k=c2,c2+1)
  f16* const sa = &stA[(c2 >> 5)*520 + (((c2 >> 3) & 3)*16 + r)*8 + (c2 & 7)];
  { f16x2 hh; hh[0]=(f16)sn[0]; hh[1]=(f16)sn[1]; *(f16x2*)sa = hh; }

  const f16* const wb_l  = WsrF + (size_t)w*16384 + l*8;     // wave's 4 ct-tiles
  const f16* const stA_l = &stA[l*8];

  // rolling P registers (prologue from zero/carried slabs 0,1)
  const f16* pp0 = P + (size_t)gb*1792;
  const f16* pp1 = P + SL + (size_t)gb*1792;
  f16x2 E0 = *(const f16x2*)(pp0 + c2);
  f16x2 E1 = *(const f16x2*)(pp1 + c2);
  f16x2 U2 = *(const f16x2*)(pp0 + 256 + c2), R2 = *(const f16x2*)(pp0 + 512 + c2), C2 = *(const f16x2*)(pp0 + 768 + c2);
  f16x2 U1 = *(const f16x2*)(pp1 + 256 + c2), R1 = *(const f16x2*)(pp1 + 512 + c2), C1 = *(const f16x2*)(pp1 + 768 + c2);

  // prologue weight slots kt0, kt1 (persist across steps; stages 6,7 refill them)
  f16x8 W0[4], W1[4];
  #pragma unroll
  for (int c = 0; c < 4; ++c) W0[c] = *(const f16x8*)(wb_l + (c*8 + 0)*512);
  #pragma unroll
  for (int c = 0; c < 4; ++c) W1[c] = *(const f16x8*)(wb_l + (c*8 + 1)*512);
  __syncthreads();

  for (int i = 0; i < nsteps; ++i){
    const int t = t0 + i;
    const f16* p2 = P + (size_t)(i+2)*SL + (size_t)gb*1792;

    f16x8 av0 = *(const f16x8*)(stA_l + 0*520);
    f16x8 av1 = *(const f16x8*)(stA_l + 1*520);
    f32x4 acc[4];
    #pragma unroll
    for (int c = 0; c < 4; ++c) acc[c] = (f32x4){0.f,0.f,0.f,0.f};

    stage2<0>(acc, W0, av0, stA_l, wb_l);
    stage2<1>(acc, W1, av1, stA_l, wb_l);
    stage2<2>(acc, W0, av0, stA_l, wb_l);
    stage2<3>(acc, W1, av1, stA_l, wb_l);

    // cold P loads for this step (before stage-4 refills: weight waits never
    // transitively wait on these HBM loads; consumed after 1-2 barriers)
    const f16x2 E2c = *(const f16x2*)(p2 + c2);
    const f16x2 Uc = *(const f16x2*)(p2 +  256 + c2), Rc = *(const f16x2*)(p2 +  512 + c2), Cc = *(const f16x2*)(p2 +  768 + c2);
    const f16x2 NU = *(const f16x2*)(p2 + 1024 + c2), NR = *(const f16x2*)(p2 + 1280 + c2), NC = *(const f16x2*)(p2 + 1536 + c2);

    stage2<4>(acc, W0, av0, stA_l, wb_l);
    stage2<5>(acc, W1, av1, stA_l, wb_l);
    stage2<6>(acc, W0, av0, stA_l, wb_l);
    stage2<7>(acc, W1, av1, stA_l, wb_l);

    if (agrp < 2){
      #pragma unroll
      for (int c = 0; c < 4; ++c){
        #pragma unroll
        for (int j = 0; j < 4; ++j)
          qg[(agrp*4 + j)*1280 + qgw + c*20] = acc[c][j];
      }
    }
    lgkm_barrier();

    // ---- phase 2a: score partials (this wave: 128 cols of row r) ----
    {
      const f32x2 q  = *(const f32x2*)&qg[r*1280 + qw2];
      const f32x2 bb = *(const f32x2*)&sb10[qw2];
      const f32x2 lk = *(const f32x2*)&sl10[qw2];
      float s0 = 0.f, s1 = 0.f, s2 = 0.f;
      #pragma unroll
      for (int j = 0; j < 2; ++j){
        const float qb = q[j] + bb[j];
        s0 += tanh_f((float)E0[j]  + qb) * lk[j];
        s1 += tanh_f((float)E1[j]  + qb) * lk[j];
        s2 += tanh_f((float)E2c[j] + qb) * lk[j];
      }
      #pragma unroll
      for (int off = 32; off; off >>= 1){
        s0 += __shfl_xor(s0, off);
        s1 += __shfl_xor(s1, off);
        s2 += __shfl_xor(s2, off);
      }
      if (l == 0){ sp[r][h][0] = s0; sp[r][h][1] = s1; sp[r][h][2] = s2; }
    }
    lgkm_barrier();

    // ---- phase 2b: softmax (redundant per lane) + GRU (2 cols/lane) ----
    {
      const float s0 = sp[r][0][0] + sp[r][1][0];
      const float s1 = sp[r][0][1] + sp[r][1][1];
      const float s2 = sp[r][0][2] + sp[r][1][2];
      const float mx = fmaxf(fmaxf(s0, s1), s2);
      const float x0 = __expf(s0 - mx), x1 = __expf(s1 - mx), x2 = __expf(s2 - mx);
      const float inv = 1.0f / (x0 + x1 + x2);
      const float pr0 = x0*inv, pr1 = x1*inv, pr2 = x2*inv;

      const f32x2 qu = *(const f32x2*)&qg[r*1280 + 320 + qw2];
      const f32x2 qr = *(const f32x2*)&qg[r*1280 + 640 + qw2];
      const f32x2 qc = *(const f32x2*)&qg[r*1280 + 960 + qw2];
      #pragma unroll
      for (int j = 0; j < 2; ++j){
        const float geu = pr2*(float)Uc[j] + pr1*(float)U1[j] + pr0*(float)U2[j];
        const float ger = pr2*(float)Rc[j] + pr1*(float)R1[j] + pr0*(float)R2[j];
        const float gec = pr2*(float)Cc[j] + pr1*(float)C1[j] + pr0*(float)C2[j];
        const float up   = sigmoid_f(qu[j] + geu + (float)NU[j]);
        const float rp   = sigmoid_f(qr[j] + ger + (float)NR[j]);
        const float cand = tanh_f(rp*qc[j] + gec + (float)NC[j]);
        sn[j] = (1.0f - up)*sn[j] + up*cand;
      }
      { f16x2 hh; hh[0]=(f16)sn[0]; hh[1]=(f16)sn[1]; *(f16x2*)sa = hh; }
      if (t == 255) *(f32x2*)(out + (size_t)gb*256 + c2) = sn;
    }
    // roll P registers forward
    E0 = E1; E1 = E2c;
    U2 = U1; U1 = Uc; R2 = R1; R1 = Rc; C2 = C1; C1 = Cc;
    lgkm_barrier();
  }

  *(f32x2*)(state + (size_t)gb*256 + c2) = sn;
}

// ---------------------------------- launch ----------------------------------
extern "C" void kernel_launch(void* const* d_in, const int* in_sizes, int n_in,
                              void* d_out, int out_size, void* d_ws, size_t ws_size,
                              hipStream_t stream)
{
  const float* X  = (const float*)d_in[0];
  const float* EK = (const float*)d_in[1];
  const float* SK = (const float*)d_in[2];
  const float* BI = (const float*)d_in[3];
  const float* LK = (const float*)d_in[4];
  const float* RS = (const float*)d_in[5];
  const float* RE = (const float*)d_in[6];
  const float* NW = (const float*)d_in[7];
  float* out = (float*)d_out;
  char* ws = (char*)d_ws;

  const size_t slabB = 1024ull * 1792ull * 2ull;   // 3,670,016 B
  const size_t XhB   = 134217728ull;               // 1024*256*256 f16
  const size_t wB    = 917504ull + 524288ull + 1048576ull;
  int CT = 4;
  if      (ws_size >= 18ull*slabB + XhB + wB) CT = 16;
  else if (ws_size >= 10ull*slabB + XhB + wB) CT = 8;

  f16* P = (f16*)ws;
  size_t poff = (size_t)(CT + 2) * slabB;
  f16* Xh    = (f16*)(ws + poff);
  f16* WcatT = (f16*)(ws + poff + XhB);
  f16* WsrF  = (f16*)(ws + poff + XhB + 917504ull);
  float* state = (float*)(ws + poff + XhB + 917504ull + 524288ull);

  hipMemsetAsync(state, 0, 1048576ull, stream);
  hipMemsetAsync(P, 0, 2ull*slabB, stream);        // zero "virtual" slabs t=-2,-1
  cast_x_kernel<<<32768, 256, 0, stream>>>(X, Xh);
  cast_w_kernel<<<2816, 256, 0, stream>>>(EK, RE, NW, SK, RS, WcatT, WsrF);

  const int nch = 256 / CT;
  for (int c = 0; c < nch; ++c){
    const int t0 = c * CT;
    const int t_start  = (c == 0) ? 0 : (t0 - 2);
    const int slab_off = (c == 0) ? 2 : 0;
    const int Mtiles = (((c == 0) ? CT : (CT + 2)) * 1024) / 128;
    gemm_f16_kernel<<<Mtiles * 14, 256, 0, stream>>>(
        Xh, WcatT, P + (size_t)slab_off * 1024 * 1792, Mtiles, t_start);
    recurrent_kernel<<<128, 1024, 0, stream>>>(P, WsrF, BI, LK, state, out, t0, CT);
  }
}